// Round 1
// baseline (103.705 us; speedup 1.0000x reference)
//
#include <hip/hip_runtime.h>

// NsoltBlockIdct3dLayer: per-64-coef block -> permute -> separable 3D 4x4x4
// orthonormal IDCT. Output flat layout == input flat layout (64 contiguous
// floats per block), since the reference reshape is a pure relabel.

#define WG 128
#define ROWS 68  // padded LDS row stride in floats (16B aligned, bank-spread)

// Orthonormal IDCT-4 matrix M[n][k] = s_k * cos(pi*(n+0.5)*k/4)
__device__ __constant__ float Mc[4][4] = {
    { 0.5f,  0.6532814824381883f,  0.5f,  0.2705980500730985f },
    { 0.5f,  0.2705980500730985f, -0.5f, -0.6532814824381883f },
    { 0.5f, -0.2705980500730985f, -0.5f,  0.6532814824381883f },
    { 0.5f, -0.6532814824381883f,  0.5f, -0.2705980500730985f },
};

__global__ __launch_bounds__(WG) void nsolt_idct3d_kernel(
    const float* __restrict__ in, float* __restrict__ out)
{
    __shared__ float lds[WG * ROWS];
    const int t = threadIdx.x;
    const size_t base = (size_t)blockIdx.x * (WG * 64);  // float offset of chunk

    // ---- Phase 1: coalesced global -> LDS (128 blocks x 64 floats) ----
#pragma unroll
    for (int m = 0; m < 16; ++m) {
        const int e = m * (WG * 4) + t * 4;          // element within chunk
        const float4 q = *reinterpret_cast<const float4*>(in + base + e);
        const int row = e >> 6;
        const int col = e & 63;
        *reinterpret_cast<float4*>(&lds[row * ROWS + col]) = q;
    }
    __syncthreads();

    float* __restrict__ myrow = &lds[t * ROWS];

    // local copy of the IDCT matrix (constant-folded under full unroll)
    float M[4][4];
#pragma unroll
    for (int a = 0; a < 4; ++a)
#pragma unroll
        for (int b = 0; b < 4; ++b) M[a][b] = Mc[a][b];

    // ---- z-pass with permutation folded into the LDS gather ----
    // A[y][x][k] = sum_z M[k][z] * V[y][x][z],
    // V[y][x][z] = coef[chunk(y&1,x&1,z&1)*8 + within(y>>1,x>>1,z>>1)]
    float A[64];
#pragma unroll
    for (int y = 0; y < 4; ++y) {
#pragma unroll
        for (int x = 0; x < 4; ++x) {
            float vz[4];
#pragma unroll
            for (int z = 0; z < 4; ++z) {
                const int chunk  = (y & 1) * 4 + (x & 1) * 2 + (z & 1);
                const int within = (y >> 1) * 4 + (x >> 1) * 2 + (z >> 1);
                vz[z] = myrow[chunk * 8 + within];
            }
#pragma unroll
            for (int k = 0; k < 4; ++k) {
                A[(y * 4 + x) * 4 + k] =
                    M[k][0] * vz[0] + M[k][1] * vz[1] +
                    M[k][2] * vz[2] + M[k][3] * vz[3];
            }
        }
    }

    // ---- x-pass (in place per y-slice): A[y][j][k] = sum_x M[j][x]*A[y][x][k] ----
#pragma unroll
    for (int y = 0; y < 4; ++y) {
        float tmp[16];
#pragma unroll
        for (int j = 0; j < 4; ++j)
#pragma unroll
            for (int k = 0; k < 4; ++k)
                tmp[j * 4 + k] =
                    M[j][0] * A[y * 16 + 0 * 4 + k] +
                    M[j][1] * A[y * 16 + 1 * 4 + k] +
                    M[j][2] * A[y * 16 + 2 * 4 + k] +
                    M[j][3] * A[y * 16 + 3 * 4 + k];
#pragma unroll
        for (int n = 0; n < 16; ++n) A[y * 16 + n] = tmp[n];
    }

    // ---- y-pass + pack results back into own LDS row ----
    // C[i][j][k] = sum_y M[i][y] * A[y][j][k]  -> row word i*16 + j*4 + k
#pragma unroll
    for (int i = 0; i < 4; ++i) {
#pragma unroll
        for (int j = 0; j < 4; ++j) {
            float r0 = M[i][0] * A[0 * 16 + j * 4 + 0] + M[i][1] * A[1 * 16 + j * 4 + 0] +
                       M[i][2] * A[2 * 16 + j * 4 + 0] + M[i][3] * A[3 * 16 + j * 4 + 0];
            float r1 = M[i][0] * A[0 * 16 + j * 4 + 1] + M[i][1] * A[1 * 16 + j * 4 + 1] +
                       M[i][2] * A[2 * 16 + j * 4 + 1] + M[i][3] * A[3 * 16 + j * 4 + 1];
            float r2 = M[i][0] * A[0 * 16 + j * 4 + 2] + M[i][1] * A[1 * 16 + j * 4 + 2] +
                       M[i][2] * A[2 * 16 + j * 4 + 2] + M[i][3] * A[3 * 16 + j * 4 + 2];
            float r3 = M[i][0] * A[0 * 16 + j * 4 + 3] + M[i][1] * A[1 * 16 + j * 4 + 3] +
                       M[i][2] * A[2 * 16 + j * 4 + 3] + M[i][3] * A[3 * 16 + j * 4 + 3];
            float4 q;
            q.x = r0; q.y = r1; q.z = r2; q.w = r3;
            *reinterpret_cast<float4*>(&myrow[i * 16 + j * 4]) = q;
        }
    }
    __syncthreads();

    // ---- Phase 3: coalesced LDS -> global ----
#pragma unroll
    for (int m = 0; m < 16; ++m) {
        const int e = m * (WG * 4) + t * 4;
        const int row = e >> 6;
        const int col = e & 63;
        const float4 q = *reinterpret_cast<const float4*>(&lds[row * ROWS + col]);
        *reinterpret_cast<float4*>(out + base + e) = q;
    }
}

extern "C" void kernel_launch(void* const* d_in, const int* in_sizes, int n_in,
                              void* d_out, int out_size, void* d_ws, size_t ws_size,
                              hipStream_t stream)
{
    const float* in = (const float*)d_in[0];
    float* out = (float*)d_out;

    const long long nBlocks = (long long)in_sizes[0] / 64;   // 64 coefs per block
    const int grid = (int)(nBlocks / WG);                    // exact: 2^20 / 128 = 8192

    hipLaunchKernelGGL(nsolt_idct3d_kernel, dim3(grid), dim3(WG), 0, stream,
                       in, out);
}

// Round 2
// 100.058 us; speedup vs baseline: 1.0364x; 1.0364x over previous
//
#include <hip/hip_runtime.h>

// NsoltBlockIdct3dLayer: per-64-coef block -> parity-permute -> separable
// 3D 4x4x4 orthonormal IDCT. Output flat layout == input flat layout.
//
// Key structure: permuted input word w = [c2 c1 c0 w2 w1 w0] holds the
// coefficient for (y,x,z) = (2*w2+c2, 2*w1+c1, 2*w0+c0). The IDCT-4
// butterfly consumes the even-frequency pair and odd-frequency pair, which
// are ADJACENT words in this layout -> z-pass reads aligned float4s from
// LDS with compile-time offsets (conflict-free), no scalar gathers.

#define WG 64
#define ROWS 68  // LDS row stride in floats; 68 = 4 mod 32 -> uniform banks

#define C1F 0.6532814824381883f
#define C3F 0.2705980500730985f

// 4-point orthonormal IDCT butterfly: in (v0=even0, v2=even1, v1=odd0, v3=odd1)
// i.e. inputs are frequency order 0,2,1,3; outputs spatial order 0..3.
#define IDCT4(a0, a2, a1, a3, r0, r1, r2, r3)            \
    {                                                    \
        const float e0 = 0.5f * ((a0) + (a2));           \
        const float e1 = 0.5f * ((a0) - (a2));           \
        const float o0 = C1F * (a1) + C3F * (a3);        \
        const float o1 = C3F * (a1) - C1F * (a3);        \
        (r0) = e0 + o0;                                  \
        (r1) = e1 + o1;                                  \
        (r2) = e1 - o1;                                  \
        (r3) = e0 - o0;                                  \
    }

__global__ __launch_bounds__(WG) void nsolt_idct3d_kernel(
    const float* __restrict__ in, float* __restrict__ out)
{
    __shared__ float lds[WG * ROWS];
    const int t = threadIdx.x;
    const size_t base = (size_t)blockIdx.x * (WG * 64);  // float offset of chunk

    // ---- Phase 1: coalesced global -> LDS (64 blocks x 64 floats) ----
#pragma unroll
    for (int m = 0; m < 16; ++m) {
        const int e = m * (WG * 4) + t * 4;          // element within chunk
        const float4 q = *reinterpret_cast<const float4*>(in + base + e);
        const int row = e >> 6;
        const int col = e & 63;
        *reinterpret_cast<float4*>(&lds[row * ROWS + col]) = q;
    }
    __syncthreads();

    float* __restrict__ myrow = &lds[t * ROWS];

    // ---- z-pass straight off LDS float4s (permutation folded into bases) ----
    // float4 at word base [c2 c1 c0 w2 0 0] = { (x=c1,z=c0), (x=c1,z=2+c0),
    //                                           (x=2+c1,z=c0), (x=2+c1,z=2+c0) }
    // A[y][x][n]: y = 2*w2+c2 spatial-freq... (y,x still frequency indices,
    // n = spatial z output)
    float A[4][4][4];
#pragma unroll
    for (int c2 = 0; c2 < 2; ++c2) {
#pragma unroll
        for (int w2 = 0; w2 < 2; ++w2) {
            const int y = 2 * w2 + c2;
#pragma unroll
            for (int c1 = 0; c1 < 2; ++c1) {
                const int b0 = c2 * 32 + c1 * 16 + w2 * 4;      // c0 = 0 (even z)
                const float4 q0 = *reinterpret_cast<const float4*>(&myrow[b0]);
                const float4 q1 = *reinterpret_cast<const float4*>(&myrow[b0 + 8]); // c0 = 1
                // x_a = c1 (even/odd depending on c1), uses .x/.y
                IDCT4(q0.x, q0.y, q1.x, q1.y,
                      A[y][c1][0], A[y][c1][1], A[y][c1][2], A[y][c1][3]);
                // x_b = 2 + c1, uses .z/.w
                IDCT4(q0.z, q0.w, q1.z, q1.w,
                      A[y][2 + c1][0], A[y][2 + c1][1], A[y][2 + c1][2], A[y][2 + c1][3]);
            }
        }
    }

    // ---- x-pass: B[y][j][n] = IDCT over x of A[y][x][n] ----
    float B[4][4][4];
#pragma unroll
    for (int y = 0; y < 4; ++y) {
#pragma unroll
        for (int n = 0; n < 4; ++n) {
            IDCT4(A[y][0][n], A[y][2][n], A[y][1][n], A[y][3][n],
                  B[y][0][n], B[y][1][n], B[y][2][n], B[y][3][n]);
        }
    }

    // ---- y-pass + pack into own LDS row: word = i*16 + j*4 + n ----
#pragma unroll
    for (int j = 0; j < 4; ++j) {
#pragma unroll
        for (int n = 0; n < 4; ++n) {
            float r0, r1, r2, r3;
            IDCT4(B[0][j][n], B[2][j][n], B[1][j][n], B[3][j][n], r0, r1, r2, r3);
            myrow[0 * 16 + j * 4 + n] = r0;
            myrow[1 * 16 + j * 4 + n] = r1;
            myrow[2 * 16 + j * 4 + n] = r2;
            myrow[3 * 16 + j * 4 + n] = r3;
        }
    }
    __syncthreads();

    // ---- Phase 3: coalesced LDS -> global ----
#pragma unroll
    for (int m = 0; m < 16; ++m) {
        const int e = m * (WG * 4) + t * 4;
        const int row = e >> 6;
        const int col = e & 63;
        const float4 q = *reinterpret_cast<const float4*>(&lds[row * ROWS + col]);
        *reinterpret_cast<float4*>(out + base + e) = q;
    }
}

extern "C" void kernel_launch(void* const* d_in, const int* in_sizes, int n_in,
                              void* d_out, int out_size, void* d_ws, size_t ws_size,
                              hipStream_t stream)
{
    const float* in = (const float*)d_in[0];
    float* out = (float*)d_out;

    const long long nBlocks = (long long)in_sizes[0] / 64;   // 64 coefs per block
    const int grid = (int)(nBlocks / WG);                    // 2^20 / 64 = 16384

    hipLaunchKernelGGL(nsolt_idct3d_kernel, dim3(grid), dim3(WG), 0, stream,
                       in, out);
}

// Round 3
// 99.960 us; speedup vs baseline: 1.0375x; 1.0010x over previous
//
#include <hip/hip_runtime.h>

// NsoltBlockIdct3dLayer: per-64-coef block -> parity permute -> separable
// 3D 4x4x4 orthonormal IDCT. Flat output layout == flat input layout.
//
// Decomposition: 4 lanes per block. Lane j = (c2,c1) = (t&3) holds words
// [16j,16j+16) of its block = all coefficients with y-parity c2, x-parity c1.
// z-pass is in-lane; x-/y-passes are distributed IDCT-4 butterflies with one
// shfl_xor(1)/(2) exchange per output pair. LDS (16 KB/WG) is used only to
// stage global<->lane-strided data; occupancy is wave-capped (32/CU), not
// LDS-capped.
//
// LDS swizzle: linear 16B-chunk f holds global chunk h(f) =
// (f&~15) | ((f&15) ^ ((f>>4)&7)). Applied on the global address for BOTH
// global_load_lds (linear dest) and the swizzled store-out; compute phases
// XOR their chunk index with (block&7). XOR affects only chunk bits 0..2 ->
// stays inside each 128B cache line (coalescing preserved) and spreads LDS
// start-banks so every access is at the uniform 8-words/bank minimum.

#define WG 256
#define C1F 0.6532814824381883f
#define C3F 0.2705980500730985f

// orthonormal IDCT-4 butterfly; inputs in frequency order (0,2,1,3)
#define IDCT4(a0, a2, a1, a3, r0, r1, r2, r3)            \
    {                                                    \
        const float e0 = 0.5f * ((a0) + (a2));           \
        const float e1 = 0.5f * ((a0) - (a2));           \
        const float o0 = C1F * (a1) + C3F * (a3);        \
        const float o1 = C3F * (a1) - C1F * (a3);        \
        (r0) = e0 + o0;                                  \
        (r1) = e1 + o1;                                  \
        (r2) = e1 - o1;                                  \
        (r3) = e0 - o0;                                  \
    }

__global__ __launch_bounds__(WG) void nsolt_idct3d_kernel(
    const float* __restrict__ in, float* __restrict__ out)
{
    __shared__ float lds[64 * 64];                 // 64 blocks x 64 floats
    const int t = threadIdx.x;
    const int w = t >> 6;                          // wave id 0..3
    const int l = t & 63;                          // lane
    const size_t wgbase = (size_t)blockIdx.x * 4096;  // floats per WG tile

    // ---- Phase 1: async global -> LDS (4 x 1KB per wave-instr), swizzled src ----
    {
        const int c   = l & 15;                    // chunk-in-row
        const int rlo = l >> 4;                    // row bits from lane
#pragma unroll
        for (int m = 0; m < 4; ++m) {
            const int r = w * 16 + m * 4 + rlo;                 // row = block idx
            const int h = (r << 4) | (c ^ rlo ^ (4 * (m & 1))); // src chunk
            const float* src = in + wgbase + (size_t)h * 4;
            __builtin_amdgcn_global_load_lds(
                (const __attribute__((address_space(1))) void*)src,
                (__attribute__((address_space(3))) void*)(&lds[(w * 256 + m * 64) * 4]),
                16, 0, 0);
        }
    }
    __syncthreads();

    // ---- Compute: 4 lanes per block ----
    const int gW = t >> 2;                 // block within WG tile [0,64)
    const int j  = t & 3;                  // (c2,c1)
    const int c1 = j & 1;
    const int c2 = j >> 1;
    const int s7 = gW & 7;
    float* __restrict__ myblk = &lds[gW * 64];

    // load my 4 input chunks (logical 4j+k), unswizzle on read
    float qa[16];
#pragma unroll
    for (int k = 0; k < 4; ++k) {
        const float4 v = *reinterpret_cast<const float4*>(
            &myblk[(((4 * j + k) ^ s7) << 2)]);
        qa[k * 4 + 0] = v.x; qa[k * 4 + 1] = v.y;
        qa[k * 4 + 2] = v.z; qa[k * 4 + 3] = v.w;
    }

    // z-pass (in-lane): local word bits [c0 w2 w1 w0]; chunk k = c0*2+w2
    float A[2][2][4];                      // [w2][w1][n]
#pragma unroll
    for (int w2 = 0; w2 < 2; ++w2) {
#pragma unroll
        for (int w1 = 0; w1 < 2; ++w1) {
            const float a0 = qa[w2 * 4 + 2 * w1];          // c0=0,w0=0 -> kz=0
            const float a2 = qa[w2 * 4 + 2 * w1 + 1];      // c0=0,w0=1 -> kz=2
            const float a1 = qa[(2 + w2) * 4 + 2 * w1];    // c0=1,w0=0 -> kz=1
            const float a3 = qa[(2 + w2) * 4 + 2 * w1 + 1];// c0=1,w0=1 -> kz=3
            IDCT4(a0, a2, a1, a3,
                  A[w2][w1][0], A[w2][w1][1], A[w2][w1][2], A[w2][w1][3]);
        }
    }

    // x-pass: k_x = 2*w1 + c1. keep/send decomposition:
    //  c1=0: keep e0=.5A0+.5A1, send e1=.5A0-.5A1 -> outputs x=0 (+), x=3 (-)
    //  c1=1: keep o1=C3*A0-C1*A1, send o0=C1*A0+C3*A1 -> outputs x=1, x=2
    const float xk0 = c1 ? C3F : 0.5f;
    const float xk1 = c1 ? -C1F : 0.5f;
    const float xs0 = c1 ? C1F : 0.5f;
    const float xs1 = c1 ? C3F : -0.5f;
    const float xsg = c1 ? -1.0f : 1.0f;

    float X[2][2][4];                      // [w2 (k_y slot)][xsel a/b][n]
#pragma unroll
    for (int w2 = 0; w2 < 2; ++w2) {
#pragma unroll
        for (int n = 0; n < 4; ++n) {
            const float A0 = A[w2][0][n], A1 = A[w2][1][n];
            const float uk = xk0 * A0 + xk1 * A1;
            const float us = xs0 * A0 + xs1 * A1;
            const float rv = __shfl_xor(us, 1, 64);
            X[w2][0][n] = uk + rv;             // x = c1 ? 1 : 0
            X[w2][1][n] = xsg * (uk - rv);     // x = c1 ? 2 : 3
        }
    }

    // y-pass: k_y = 2*w2 + c2, exchange across lane^2
    const float yk0 = c2 ? C3F : 0.5f;
    const float yk1 = c2 ? -C1F : 0.5f;
    const float ys0 = c2 ? C1F : 0.5f;
    const float ys1 = c2 ? C3F : -0.5f;
    const float ysg = c2 ? -1.0f : 1.0f;

    const int xa = c1 ? 1 : 0, xb = c1 ? 2 : 3;
    const int ya = c2 ? 1 : 0, yb = c2 ? 2 : 3;

#pragma unroll
    for (int xs = 0; xs < 2; ++xs) {
        float ra[4], rb[4];
#pragma unroll
        for (int n = 0; n < 4; ++n) {
            const float A0 = X[0][xs][n], A1 = X[1][xs][n];
            const float uk = yk0 * A0 + yk1 * A1;
            const float us = ys0 * A0 + ys1 * A1;
            const float rv = __shfl_xor(us, 2, 64);
            ra[n] = uk + rv;                   // y = c2 ? 1 : 0
            rb[n] = ysg * (uk - rv);           // y = c2 ? 2 : 3
        }
        const int xv = xs ? xb : xa;
        float4 va; va.x = ra[0]; va.y = ra[1]; va.z = ra[2]; va.w = ra[3];
        float4 vb; vb.x = rb[0]; vb.y = rb[1]; vb.z = rb[2]; vb.w = rb[3];
        *reinterpret_cast<float4*>(&myblk[(((ya * 4 + xv) ^ s7) << 2)]) = va;
        *reinterpret_cast<float4*>(&myblk[(((yb * 4 + xv) ^ s7) << 2)]) = vb;
    }
    __syncthreads();

    // ---- Phase 3: linear LDS read -> swizzled coalesced global store ----
    {
        const int c   = l & 15;
        const int rlo = l >> 4;
#pragma unroll
        for (int m = 0; m < 4; ++m) {
            const int f = w * 256 + m * 64 + l;                 // linear chunk
            const float4 v = *reinterpret_cast<const float4*>(&lds[f * 4]);
            const int r = w * 16 + m * 4 + rlo;
            const int h = (r << 4) | (c ^ rlo ^ (4 * (m & 1)));
            *reinterpret_cast<float4*>(out + wgbase + (size_t)h * 4) = v;
        }
    }
}

extern "C" void kernel_launch(void* const* d_in, const int* in_sizes, int n_in,
                              void* d_out, int out_size, void* d_ws, size_t ws_size,
                              hipStream_t stream)
{
    const float* in = (const float*)d_in[0];
    float* out = (float*)d_out;

    const long long nBlocks = (long long)in_sizes[0] / 64;   // 64 coefs per block
    const int grid = (int)(nBlocks / 64);                    // 64 blocks per WG -> 16384

    hipLaunchKernelGGL(nsolt_idct3d_kernel, dim3(grid), dim3(WG), 0, stream,
                       in, out);
}

// Round 5
// 83.209 us; speedup vs baseline: 1.2463x; 1.2013x over previous
//
#include <hip/hip_runtime.h>

// NsoltBlockIdct3dLayer: per-64-coef block -> parity permute -> separable
// 3D 4x4x4 orthonormal IDCT. Flat output layout == flat input layout.
//
// Barrier-free streaming form:
//  - tile = 16 blocks = 1024 floats = 4 KB; each wave owns a PRIVATE 4 KB LDS
//    region and processes NT consecutive tiles -> no __syncthreads anywhere.
//  - depth-2 register prefetch (ping-pong sA/sB): loads for tile k+2 are
//    issued immediately after tile k's ds_write consumes those registers, so
//    in steady state the wave never stalls on HBM (copy-kernel profile).
//  - 4 lanes per block: lane j=(c2,c1) holds words [16j,16j+16). z-pass is
//    in-lane; x/y passes are distributed IDCT-4 butterflies, one shfl_xor
//    per output pair.
//  - XOR chunk swizzle swz(c) = (c&~15)|((c&15)^((c>>4)&7)) applied at the
//    ds_write scatter and inverted (involution) at the global store; every
//    LDS phase is at the uniform 8-words/bank minimum.

#define WG 256
#define NT 8                       // tiles per wave
#define C1F 0.6532814824381883f
#define C3F 0.2705980500730985f

typedef float vfloat4 __attribute__((ext_vector_type(4)));

// orthonormal IDCT-4 butterfly; inputs in frequency order (0,2,1,3)
#define IDCT4(a0, a2, a1, a3, r0, r1, r2, r3)            \
    {                                                    \
        const float e0 = 0.5f * ((a0) + (a2));           \
        const float e1 = 0.5f * ((a0) - (a2));           \
        const float o0 = C1F * (a1) + C3F * (a3);        \
        const float o1 = C3F * (a1) - C1F * (a3);        \
        (r0) = e0 + o0;                                  \
        (r1) = e1 + o1;                                  \
        (r2) = e1 - o1;                                  \
        (r3) = e0 - o0;                                  \
    }

__device__ __forceinline__ int swz(int c) {
    return (c & ~15) | ((c & 15) ^ ((c >> 4) & 7));
}

__device__ __forceinline__ void load_tile(vfloat4 s[4],
                                          const float* __restrict__ in,
                                          size_t tb, int l) {
#pragma unroll
    for (int m = 0; m < 4; ++m)
        s[m] = *reinterpret_cast<const vfloat4*>(in + tb + m * 256 + l * 4);
}

__device__ __forceinline__ void process_tile(
    vfloat4 s[4], bool doPrefetch, size_t nextTb,
    const float* __restrict__ in, float* __restrict__ out,
    size_t tb, float* __restrict__ region, int l)
{
    // ---- staging: regs -> LDS (swizzled scatter), consumes s ----
#pragma unroll
    for (int m = 0; m < 4; ++m) {
        const int c = m * 64 + l;
        *reinterpret_cast<vfloat4*>(&region[swz(c) * 4]) = s[m];
    }

    // ---- prefetch tile k+2 into the same registers (issues now, waits later) ----
    if (doPrefetch) {
#pragma unroll
        for (int m = 0; m < 4; ++m)
            s[m] = *reinterpret_cast<const vfloat4*>(in + nextTb + m * 256 + l * 4);
    }

    // ---- compute: 4 lanes per block ----
    const int gW = l >> 2;                 // block within tile [0,16)
    const int j  = l & 3;                  // (c2,c1)
    const int c1 = j & 1;
    const int c2 = j >> 1;
    const int s7 = gW & 7;
    float* __restrict__ myblk = &region[gW * 64];

    float qa[16];
#pragma unroll
    for (int k = 0; k < 4; ++k) {
        const vfloat4 v = *reinterpret_cast<const vfloat4*>(
            &myblk[(((4 * j + k) ^ s7) << 2)]);
        qa[k * 4 + 0] = v.x; qa[k * 4 + 1] = v.y;
        qa[k * 4 + 2] = v.z; qa[k * 4 + 3] = v.w;
    }

    // z-pass (in-lane): local word bits [c0 w2 w1 w0]; chunk k = c0*2+w2
    float A[2][2][4];                      // [w2][w1][n]
#pragma unroll
    for (int w2 = 0; w2 < 2; ++w2) {
#pragma unroll
        for (int w1 = 0; w1 < 2; ++w1) {
            const float a0 = qa[w2 * 4 + 2 * w1];
            const float a2 = qa[w2 * 4 + 2 * w1 + 1];
            const float a1 = qa[(2 + w2) * 4 + 2 * w1];
            const float a3 = qa[(2 + w2) * 4 + 2 * w1 + 1];
            IDCT4(a0, a2, a1, a3,
                  A[w2][w1][0], A[w2][w1][1], A[w2][w1][2], A[w2][w1][3]);
        }
    }

    // x-pass: keep/send butterfly across lane^1
    const float xk0 = c1 ? C3F : 0.5f;
    const float xk1 = c1 ? -C1F : 0.5f;
    const float xs0 = c1 ? C1F : 0.5f;
    const float xs1 = c1 ? C3F : -0.5f;
    const float xsg = c1 ? -1.0f : 1.0f;

    float X[2][2][4];
#pragma unroll
    for (int w2 = 0; w2 < 2; ++w2) {
#pragma unroll
        for (int n = 0; n < 4; ++n) {
            const float A0 = A[w2][0][n], A1 = A[w2][1][n];
            const float uk = xk0 * A0 + xk1 * A1;
            const float us = xs0 * A0 + xs1 * A1;
            const float rv = __shfl_xor(us, 1, 64);
            X[w2][0][n] = uk + rv;
            X[w2][1][n] = xsg * (uk - rv);
        }
    }

    // y-pass: keep/send butterfly across lane^2, pack to LDS (in place)
    const float yk0 = c2 ? C3F : 0.5f;
    const float yk1 = c2 ? -C1F : 0.5f;
    const float ys0 = c2 ? C1F : 0.5f;
    const float ys1 = c2 ? C3F : -0.5f;
    const float ysg = c2 ? -1.0f : 1.0f;

    const int xa = c1 ? 1 : 0, xb = c1 ? 2 : 3;
    const int ya = c2 ? 1 : 0, yb = c2 ? 2 : 3;

#pragma unroll
    for (int xs = 0; xs < 2; ++xs) {
        float ra[4], rb[4];
#pragma unroll
        for (int n = 0; n < 4; ++n) {
            const float A0 = X[0][xs][n], A1 = X[1][xs][n];
            const float uk = yk0 * A0 + yk1 * A1;
            const float us = ys0 * A0 + ys1 * A1;
            const float rv = __shfl_xor(us, 2, 64);
            ra[n] = uk + rv;
            rb[n] = ysg * (uk - rv);
        }
        const int xv = xs ? xb : xa;
        vfloat4 va; va.x = ra[0]; va.y = ra[1]; va.z = ra[2]; va.w = ra[3];
        vfloat4 vb; vb.x = rb[0]; vb.y = rb[1]; vb.z = rb[2]; vb.w = rb[3];
        *reinterpret_cast<vfloat4*>(&myblk[(((ya * 4 + xv) ^ s7) << 2)]) = va;
        *reinterpret_cast<vfloat4*>(&myblk[(((yb * 4 + xv) ^ s7) << 2)]) = vb;
    }

    // ---- drain: linear LDS read -> swizzled nontemporal coalesced store ----
#pragma unroll
    for (int m = 0; m < 4; ++m) {
        const int f = m * 64 + l;
        const vfloat4 v = *reinterpret_cast<const vfloat4*>(&region[f * 4]);
        __builtin_nontemporal_store(
            v, reinterpret_cast<vfloat4*>(out + tb + (size_t)swz(f) * 4));
    }
}

__global__ __launch_bounds__(WG, 2) void nsolt_idct3d_kernel(
    const float* __restrict__ in, float* __restrict__ out)
{
    __shared__ float lds[4 * 1024];                // 4 waves x private 4KB
    const int t = threadIdx.x;
    const int l = t & 63;
    const int wv = blockIdx.x * (WG / 64) + (t >> 6);
    float* __restrict__ region = &lds[(t >> 6) * 1024];

    const size_t tile0 = (size_t)wv * NT;

    vfloat4 sA[4], sB[4];
    load_tile(sA, in, tile0 * 1024, l);
    load_tile(sB, in, (tile0 + 1) * 1024, l);

    for (int it = 0; it < NT; it += 2) {
        process_tile(sA, it + 2 < NT, (tile0 + it + 2) * 1024,
                     in, out, (tile0 + it) * 1024, region, l);
        process_tile(sB, it + 3 < NT, (tile0 + it + 3) * 1024,
                     in, out, (tile0 + it + 1) * 1024, region, l);
    }
}

extern "C" void kernel_launch(void* const* d_in, const int* in_sizes, int n_in,
                              void* d_out, int out_size, void* d_ws, size_t ws_size,
                              hipStream_t stream)
{
    const float* in = (const float*)d_in[0];
    float* out = (float*)d_out;

    const long long nfloat = (long long)in_sizes[0];
    const long long nTiles = nfloat / 1024;                  // 65536
    const int grid = (int)(nTiles / (NT * (WG / 64)));       // 2048 WGs

    hipLaunchKernelGGL(nsolt_idct3d_kernel, dim3(grid), dim3(WG), 0, stream,
                       in, out);
}